// Round 1
// 99.456 us; speedup vs baseline: 1.0060x; 1.0060x over previous
//
#include <hip/hip_runtime.h>
#include <hip/hip_bf16.h>
#include <math.h>

// Problem constants
#define N_TOK 4096
#define W 512
#define F_TOT 1024
#define FW (F_TOT * W)   // 524288

// Workspace layout (bytes). Harness re-poisons the FULL 256 MiB ws every
// iter (~45 us, the dominant fillBufferAligned dispatches) regardless of
// how much we use — so layout size is irrelevant to dur_us; only our
// kernel time + launch count are controllable.
#define OFF_CNT     0                     // 512 uints: per-segment nnz
#define OFF_PARTIAL 4096                  // 512 floats: per-segment max|f|
#define OFF_E       8192                  // FW uints  (2 MB) nonzero elem ids
#define OFF_T       (8192 + FW * 4)       // FW floats (2 MB) signed relu(|raw|-TAU)
#define OFF_C       (8192 + FW * 8)       // FW floats (2 MB) scaled freqs

typedef __attribute__((ext_vector_type(8))) short bf16x8;
typedef __attribute__((ext_vector_type(4))) float f32x4;

__device__ __forceinline__ bf16x8 pack8(float a0, float a1, float a2, float a3,
                                        float a4, float a5, float a6, float a7) {
  alignas(16) __hip_bfloat16 o[8];
  o[0] = __float2bfloat16(a0); o[1] = __float2bfloat16(a1);
  o[2] = __float2bfloat16(a2); o[3] = __float2bfloat16(a3);
  o[4] = __float2bfloat16(a4); o[5] = __float2bfloat16(a5);
  o[6] = __float2bfloat16(a6); o[7] = __float2bfloat16(a7);
  return *(const bf16x8*)o;
}

// Kernel 1 (640 blocks x 256): fused {compact+maxf} and {LN + B-convert +
// GEMM + GELU}. The two roles are data-independent because win() is
// deferred to the spectral kernel (thr compaction only needs |raw|>TAU).
//
//  - blocks 0..127 (first, so they overlap the GEMM wave-front): 4 waves,
//    each wave owns segment g = bid*4+wv of 1024 elems. Ballot/popc
//    wave-compaction into eArr/tArr/cArr[g*1024 ..), count -> cnt[g],
//    max|0.8*freq| -> partial[g]. No atomics, no zero-init ordering.
//  - blocks 128..639: GEMM 64x64 tile (tm=bid2>>3, tn=bid2&7), 4 waves,
//    wave wv computes rows wv*16..+15. Phases (64 KB LDS, time-shared):
//      A: per-wave LN of its 16 x-rows -> LDS bf16 (XOR-swizzled
//         byte ^= (row&7)<<4 — row-major [64][512] bf16 would be a same-
//         bank 16-lane conflict on ds_read_b128 otherwise; 2-way is free),
//         then all 16 A-frags -> 64 VGPRs (lane m=lane&15 reads row wv*16+m).
//      B: stage w_loc f32 -> bf16 LDS, fully-coalesced global reads
//         (thread t reads row i*4+wv, cols lane*8..+7), same swizzle.
//      C: 16 K-iters x 4 MFMA 16x16x32 bf16 with next-k B-frag prefetch
//         from LDS; GELU(erf) epilogue. C/D: col=lane&15, row=q*4+reg.
__global__ __launch_bounds__(256) void fused_main(
    const float* __restrict__ x, const float* __restrict__ freq,
    const float* __restrict__ alpha, const float* __restrict__ gate,
    const float* __restrict__ gamma, const float* __restrict__ beta,
    const float* __restrict__ wloc, const float* __restrict__ bias,
    float* __restrict__ out, unsigned* __restrict__ cnt,
    float* __restrict__ partial, unsigned* __restrict__ eArr,
    float* __restrict__ tArr, float* __restrict__ cArr) {
  __shared__ alignas(128) char lds_raw[65536];
  const int bid = blockIdx.x, t = threadIdx.x;
  const int wv = t >> 6, lane = t & 63;

  if (bid < 128) {  // ---- compact path ----
    const int g = bid * 4 + wv;
    const int base = g * 1024;
    unsigned c = 0;
    float mx = 0.0f;
#pragma unroll
    for (int j = 0; j < 16; ++j) {
      const int e = base + j * 64 + lane;
      const float f = freq[e] * 0.8f;
      const float raw = alpha[e] * gate[e];
      const float v = fabsf(raw) - 1e-3f;  // TAU
      mx = fmaxf(mx, fabsf(f));
      const bool pred = v > 0.0f;
      const unsigned long long mk = __ballot(pred);
      if (pred) {
        const unsigned idx = base + c + (unsigned)__popcll(mk & ((1ull << lane) - 1ull));
        eArr[idx] = (unsigned)e;
        tArr[idx] = copysignf(v, raw);
        cArr[idx] = f;
      }
      c += (unsigned)__popcll(mk);
    }
#pragma unroll
    for (int mm = 32; mm > 0; mm >>= 1) mx = fmaxf(mx, __shfl_xor(mx, mm));
    if (lane == 0) { cnt[g] = c; partial[g] = mx; }
    return;
  }

  // ---- GEMM path ----
  const int bid2 = bid - 128;
  const int tm = bid2 >> 3;  // 64 row tiles of 64
  const int tn = bid2 & 7;   // 8 col tiles of 64
  const int m = lane & 15, q = lane >> 4;

  const float4 g0 = ((const float4*)gamma)[lane * 2];
  const float4 g1 = ((const float4*)gamma)[lane * 2 + 1];
  const float4 be0 = ((const float4*)beta)[lane * 2];
  const float4 be1 = ((const float4*)beta)[lane * 2 + 1];

  // Phase A: LN 16 rows -> LDS (swizzled bf16)
  for (int rr = 0; rr < 16; ++rr) {
    const int lrow = wv * 16 + rr;
    const float4* xr = (const float4*)(x + (tm * 64 + lrow) * W);
    const float4 p0 = xr[lane * 2];
    const float4 p1 = xr[lane * 2 + 1];
    float s  = p0.x + p0.y + p0.z + p0.w + p1.x + p1.y + p1.z + p1.w;
    float ss = p0.x*p0.x + p0.y*p0.y + p0.z*p0.z + p0.w*p0.w
             + p1.x*p1.x + p1.y*p1.y + p1.z*p1.z + p1.w*p1.w;
#pragma unroll
    for (int mm = 32; mm > 0; mm >>= 1) {
      s  += __shfl_xor(s, mm);
      ss += __shfl_xor(ss, mm);
    }
    const float mu = s * (1.0f / W);
    const float rstd = rsqrtf(ss * (1.0f / W) - mu * mu + 1e-5f);
    const bf16x8 o = pack8((p0.x - mu) * rstd * g0.x + be0.x,
                           (p0.y - mu) * rstd * g0.y + be0.y,
                           (p0.z - mu) * rstd * g0.z + be0.z,
                           (p0.w - mu) * rstd * g0.w + be0.w,
                           (p1.x - mu) * rstd * g1.x + be1.x,
                           (p1.y - mu) * rstd * g1.y + be1.y,
                           (p1.z - mu) * rstd * g1.z + be1.z,
                           (p1.w - mu) * rstd * g1.w + be1.w);
    *(bf16x8*)(lds_raw + lrow * 1024 + ((lane * 16) ^ ((lrow & 7) << 4))) = o;
  }
  __syncthreads();

  // A-fragments to registers (64 VGPRs), freeing LDS for B
  bf16x8 a[16];
  {
    const int lrow = wv * 16 + m;
    const char* rbase = lds_raw + lrow * 1024;
    const int swz = (lrow & 7) << 4;
#pragma unroll
    for (int kk = 0; kk < 16; ++kk)
      a[kk] = *(const bf16x8*)(rbase + (((kk * 32 + q * 8) * 2) ^ swz));
  }
  __syncthreads();

  // Phase B: stage B tile (w_loc f32 -> bf16) into same LDS, coalesced
  {
    const float* wbase = wloc + (tn * 64) * W;
#pragma unroll
    for (int i = 0; i < 16; ++i) {
      const int n = i * 4 + wv;
      const float4* wr = (const float4*)(wbase + n * W);
      const float4 u0 = wr[lane * 2];
      const float4 u1 = wr[lane * 2 + 1];
      const bf16x8 o = pack8(u0.x, u0.y, u0.z, u0.w, u1.x, u1.y, u1.z, u1.w);
      *(bf16x8*)(lds_raw + n * 1024 + ((lane * 16) ^ ((n & 7) << 4))) = o;
    }
  }
  __syncthreads();

  // Phase C: MFMA with next-k B prefetch
  f32x4 acc[4] = {};
  bf16x8 bc[4], bn[4];
#pragma unroll
  for (int j = 0; j < 4; ++j) {
    const int n = j * 16 + m;
    bc[j] = *(const bf16x8*)(lds_raw + n * 1024 + (((q * 8) * 2) ^ ((n & 7) << 4)));
  }
#pragma unroll
  for (int kk = 0; kk < 16; ++kk) {
    if (kk < 15) {
#pragma unroll
      for (int j = 0; j < 4; ++j) {
        const int n = j * 16 + m;
        const int kb = ((kk + 1) * 32 + q * 8) * 2;
        bn[j] = *(const bf16x8*)(lds_raw + n * 1024 + (kb ^ ((n & 7) << 4)));
      }
    }
#pragma unroll
    for (int j = 0; j < 4; ++j)
      acc[j] = __builtin_amdgcn_mfma_f32_16x16x32_bf16(a[kk], bc[j], acc[j], 0, 0, 0);
#pragma unroll
    for (int j = 0; j < 4; ++j) bc[j] = bn[j];
  }

  // Epilogue: bias + exact-erf GELU
#pragma unroll
  for (int j = 0; j < 4; ++j) {
    const int col = tn * 64 + j * 16 + m;
    const float bv = bias[col];
#pragma unroll
    for (int r = 0; r < 4; ++r) {
      const int row = tm * 64 + wv * 16 + q * 4 + r;
      const float v = acc[j][r] + bv;
      out[row * W + col] = 0.5f * v * (1.0f + erff(v * 0.70710678118654752f));
    }
  }
}

// Kernel 2: spectral accumulation + RMS norm + residual add. Early-exits
// on sum(cnt)==0 (the actual inputs: |alpha*gate| < TAU everywhere).
// Recomputes LN per row in f32 (xn buffer eliminated); win() computed
// inline per compacted element from denom = max(partial).
__global__ __launch_bounds__(64) void spectral_final(
    const float* __restrict__ x, const float* __restrict__ gamma,
    const float* __restrict__ beta, const unsigned* __restrict__ cnt,
    const float* __restrict__ partial, const unsigned* __restrict__ eArr,
    const float* __restrict__ tArr, const float* __restrict__ cArr,
    float* __restrict__ out) {
  const int lane = threadIdx.x;
  unsigned tot = 0;
#pragma unroll
  for (int j = 0; j < 8; ++j) tot += cnt[lane + j * 64];
#pragma unroll
  for (int mm = 32; mm > 0; mm >>= 1) tot += __shfl_xor(tot, mm);
  if (tot == 0) return;

  float mx = 0.0f;
#pragma unroll
  for (int j = 0; j < 8; ++j) mx = fmaxf(mx, partial[lane + j * 64]);
#pragma unroll
  for (int mm = 32; mm > 0; mm >>= 1) mx = fmaxf(mx, __shfl_xor(mx, mm));
  const bool tiny = mx < 1e-8f;
  const float inv = tiny ? 0.0f : 1.0f / mx;

  float gm[8], bt[8];
#pragma unroll
  for (int j = 0; j < 8; ++j) {
    gm[j] = gamma[lane + j * 64];
    bt[j] = beta[lane + j * 64];
  }

  for (int n = blockIdx.x; n < N_TOK; n += gridDim.x) {
    float xv[8], s = 0.0f, ss = 0.0f;
#pragma unroll
    for (int j = 0; j < 8; ++j) {
      xv[j] = x[n * W + lane + j * 64];
      s += xv[j];
      ss += xv[j] * xv[j];
    }
#pragma unroll
    for (int mm = 32; mm > 0; mm >>= 1) {
      s += __shfl_xor(s, mm);
      ss += __shfl_xor(ss, mm);
    }
    const float mu = s * (1.0f / W);
    const float rstd = rsqrtf(ss * (1.0f / W) - mu * mu + 1e-5f);
#pragma unroll
    for (int j = 0; j < 8; ++j) xv[j] = (xv[j] - mu) * rstd * gm[j] + bt[j];

    float h[8] = {0, 0, 0, 0, 0, 0, 0, 0};
    for (int g = 0; g < 512; ++g) {
      const unsigned cs = cnt[g];
      const unsigned b0 = (unsigned)g * 1024u;
      for (unsigned i = 0; i < cs; ++i) {
        const unsigned e = eArr[b0 + i];
        const int we = (int)(e & (W - 1));
        if ((we & 63) == lane) {
          const int j = we >> 6;
          const float f = cArr[b0 + i];
          const float r = f * inv;
          const float win = tiny ? 1.0f : expf(-6.0f * r * r);
          h[j] += tArr[b0 + i] * win * sinf(xv[j] * f);
        }
      }
    }
    float s2 = 0.0f;
#pragma unroll
    for (int j = 0; j < 8; ++j) s2 += h[j] * h[j];
#pragma unroll
    for (int mm = 32; mm > 0; mm >>= 1) s2 += __shfl_xor(s2, mm);
    const float sc = 0.25f / sqrtf(s2 * (1.0f / W) + 1e-8f);
#pragma unroll
    for (int j = 0; j < 8; ++j) out[n * W + lane + j * 64] += sc * h[j];
  }
}

extern "C" void kernel_launch(void* const* d_in, const int* in_sizes, int n_in,
                              void* d_out, int out_size, void* d_ws, size_t ws_size,
                              hipStream_t stream) {
  const float* x     = (const float*)d_in[0];
  const float* freq  = (const float*)d_in[1];
  const float* alpha = (const float*)d_in[2];
  const float* gate  = (const float*)d_in[3];
  const float* gamma = (const float*)d_in[4];
  const float* beta  = (const float*)d_in[5];
  const float* wloc  = (const float*)d_in[6];
  const float* bloc  = (const float*)d_in[7];
  float* out = (float*)d_out;

  char* ws = (char*)d_ws;
  unsigned* cnt  = (unsigned*)(ws + OFF_CNT);
  float* partial = (float*)(ws + OFF_PARTIAL);
  unsigned* eArr = (unsigned*)(ws + OFF_E);
  float* tArr    = (float*)(ws + OFF_T);
  float* cArr    = (float*)(ws + OFF_C);

  hipLaunchKernelGGL(fused_main, dim3(640), dim3(256), 0, stream,
                     x, freq, alpha, gate, gamma, beta, wloc, bloc,
                     out, cnt, partial, eArr, tArr, cArr);
  hipLaunchKernelGGL(spectral_final, dim3(512), dim3(64), 0, stream,
                     x, gamma, beta, cnt, partial, eArr, tArr, cArr, out);
}